// Round 1
// baseline (1536.015 us; speedup 1.0000x reference)
//
#include <hip/hip_runtime.h>

// Shapes (hardcoded for this problem instance):
//   x: (2, 384, 256, 256) fp32, w_qkv: (1152, 384) fp32, w_proj: (384, 384) fp32
//   out: (2, 384, 256, 256) fp32.  WS=8, NH=8, HD=48.  256%8==0 -> no reflect pad.
// pix' = b*65536 + win*64 + t  (window-ordered pixel index, win = wy*32+wx, t = ty*8+tx)

#define NPIX 131072   // 2*256*256
#define KDIM 384
#define SCALE 0.14433756729740643f  // 48^-0.5

typedef __attribute__((ext_vector_type(8))) short bf16x8;   // 8 bf16 in 4 VGPRs
typedef __attribute__((ext_vector_type(4))) float floatx4;

__device__ __forceinline__ unsigned short f2b(float f) {
  union { float f; unsigned u; } v; v.f = f;
  return (unsigned short)((v.u + 0x7FFFu + ((v.u >> 16) & 1u)) >> 16);  // RNE
}

__device__ __forceinline__ floatx4 mfma_bf16(bf16x8 a, bf16x8 b, floatx4 c) {
  return __builtin_amdgcn_mfma_f32_16x16x32_bf16(a, b, c, 0, 0, 0);
}

// ---------------------------------------------------------------- weights cast
__global__ __launch_bounds__(256) void wcvt(const float* __restrict__ wq,
                                            const float* __restrict__ wp,
                                            unsigned short* __restrict__ wqb,
                                            unsigned short* __restrict__ wpb) {
  int i = blockIdx.x * 256 + threadIdx.x;
  if (i < 1152 * 384) wqb[i] = f2b(wq[i]);
  if (i < 384 * 384)  wpb[i] = f2b(wp[i]);
}

// ------------------------------------------- x (b,c,raster) fp32 -> xT[pix'][c] bf16
// block: (b, wy, wxg of 4 windows, cg of 32 channels); 2*32*8*12 = 6144 blocks
__global__ __launch_bounds__(256) void transpose_cast(const float* __restrict__ x,
                                                      unsigned short* __restrict__ xT) {
  __shared__ unsigned short sT[256 * 40];  // [pixloc][c], stride 40 (16B aligned rows)
  int id = blockIdx.x;
  int cg = id % 12; id /= 12;
  int wxg = id % 8; id /= 8;
  int wy = id % 32; id /= 32;
  int b = id;
  int tid = threadIdx.x;
  const float* xb = x + ((size_t)(b * 384 + cg * 32)) * 65536 + (size_t)(wy * 8) * 256 + wxg * 32;
#pragma unroll 4
  for (int it = 0; it < 32; ++it) {
    int e = it * 256 + tid;
    int c = e >> 8, rem = e & 255, y = rem >> 5, xx = rem & 31;
    float v = xb[(size_t)c * 65536 + y * 256 + xx];
    int pixloc = (xx >> 3) * 64 + y * 8 + (xx & 7);
    sT[pixloc * 40 + c] = f2b(v);
  }
  __syncthreads();
  int wl = tid >> 6, t = tid & 63;
  size_t pix = (size_t)b * 65536 + (size_t)(wy * 32 + wxg * 4 + wl) * 64 + t;
  unsigned short* dst = xT + pix * 384 + cg * 32;
  const unsigned short* src = &sT[tid * 40];
#pragma unroll
  for (int q = 0; q < 4; ++q)
    *(uint4*)(dst + q * 8) = *(const uint4*)(src + q * 8);
}

// ---------------------------------------------------------------- bf16 MFMA GEMM
// C[m][n] = sum_k A[m][k] * B[n][k]; A [M][K] bf16, B [N][K] bf16, K%64==0.
// MODE 0: store bf16 C[m*N+n]  (qkv).  MODE 1: scatter fp32 to (b,o,raster) (out).
// 128x128 tile, BK=64, 4 waves each 64x64 (4x4 MFMA tiles), XOR-swizzled LDS.
template <int MODE>
__global__ __launch_bounds__(256, 2) void gemm_bt(const unsigned short* __restrict__ A,
                                                  const unsigned short* __restrict__ B,
                                                  void* __restrict__ Cout,
                                                  int M, int N, int K) {
  __shared__ unsigned short As[128 * 64];  // [(m*8 + (kb^(m&7)))*8], 16 KB
  __shared__ unsigned short Bs[128 * 64];
  const int tid = threadIdx.x;
  const int Mbase = blockIdx.y * 128;
  const int Nbase = blockIdx.x * 128;
  const int wave = tid >> 6, lane = tid & 63;
  const int wm = wave >> 1, wn = wave & 1;
  const int l16 = lane & 15, quad = lane >> 4;
  const int Kv = K >> 3;  // row stride in uint4

  floatx4 acc[4][4];
#pragma unroll
  for (int mt = 0; mt < 4; ++mt)
#pragma unroll
    for (int nt = 0; nt < 4; ++nt) acc[mt][nt] = 0.f;

  const int mrow = tid >> 3;   // 0..31 (row within group of 32)
  const int kb = tid & 7;      // 16B chunk within 64-k tile
  const int kTiles = K >> 6;
  for (int kt = 0; kt < kTiles; ++kt) {
    const uint4* Ag = (const uint4*)(A + (size_t)Mbase * K) + kt * 8;
    const uint4* Bg = (const uint4*)(B + (size_t)Nbase * K) + kt * 8;
    uint4 va[4], vb[4];
#pragma unroll
    for (int j = 0; j < 4; ++j) {
      int m = j * 32 + mrow;
      va[j] = Ag[(size_t)m * Kv + kb];
      vb[j] = Bg[(size_t)m * Kv + kb];
    }
    __syncthreads();
#pragma unroll
    for (int j = 0; j < 4; ++j) {
      int m = j * 32 + mrow;
      int sw = kb ^ (m & 7);
      *(uint4*)&As[(m * 8 + sw) * 8] = va[j];
      *(uint4*)&Bs[(m * 8 + sw) * 8] = vb[j];
    }
    __syncthreads();
#pragma unroll
    for (int s = 0; s < 2; ++s) {
      bf16x8 af[4], bfr[4];
#pragma unroll
      for (int mt = 0; mt < 4; ++mt) {
        int m = wm * 64 + mt * 16 + l16;
        int kk = (s * 4 + quad) ^ (m & 7);
        af[mt] = *(const bf16x8*)&As[(m * 8 + kk) * 8];
      }
#pragma unroll
      for (int nt = 0; nt < 4; ++nt) {
        int n = wn * 64 + nt * 16 + l16;
        int kk = (s * 4 + quad) ^ (n & 7);
        bfr[nt] = *(const bf16x8*)&Bs[(n * 8 + kk) * 8];
      }
#pragma unroll
      for (int mt = 0; mt < 4; ++mt)
#pragma unroll
        for (int nt = 0; nt < 4; ++nt)
          acc[mt][nt] = mfma_bf16(af[mt], bfr[nt], acc[mt][nt]);
    }
  }

  // epilogue: C/D layout col = l16 (n), row = quad*4 + reg (m)
#pragma unroll
  for (int mt = 0; mt < 4; ++mt) {
#pragma unroll
    for (int nt = 0; nt < 4; ++nt) {
#pragma unroll
      for (int r = 0; r < 4; ++r) {
        int m = Mbase + wm * 64 + mt * 16 + quad * 4 + r;
        int n = Nbase + wn * 64 + nt * 16 + l16;
        float val = acc[mt][nt][r];
        if (MODE == 0) {
          ((unsigned short*)Cout)[(size_t)m * N + n] = f2b(val);
        } else {
          int b = n >> 16, rr = n & 65535;
          int win = rr >> 6, t = rr & 63;
          int hh = (win >> 5) * 8 + (t >> 3);
          int ww = (win & 31) * 8 + (t & 7);
          ((float*)Cout)[((size_t)(b * 384 + m)) * 65536 + hh * 256 + ww] = val;
        }
      }
    }
  }
}

// ---------------------------------------------------------------- window attention
// block = (window, head); 256 threads (4 waves, wave w owns q-rows [16w,16w+16))
__global__ __launch_bounds__(256, 2) void attn_kernel(const unsigned short* __restrict__ qkv,
                                                      unsigned short* __restrict__ ao) {
  __shared__ unsigned short sQ[64 * 72];  // [t][d], d padded 48->64, stride 72
  __shared__ unsigned short sK[64 * 72];  // [u][d]
  __shared__ unsigned short sV[48 * 72];  // [d][u], stride 72
  __shared__ unsigned short sP[64 * 72];  // [t][u]
  const int wh = blockIdx.x;
  const int wing = wh >> 3, h = wh & 7;
  const int wb = wing * 64;  // pix' base
  const int tid = threadIdx.x;

  {  // load q,k transposed (coalesced 2B reads along t), v direct rows
    int t = tid & 63, dr = tid >> 6;
#pragma unroll
    for (int d0 = 0; d0 < 48; d0 += 4) {
      int d = d0 + dr;
      sQ[t * 72 + d] = qkv[(size_t)(h * 48 + d) * NPIX + wb + t];
      sK[t * 72 + d] = qkv[(size_t)(384 + h * 48 + d) * NPIX + wb + t];
    }
#pragma unroll
    for (int d0 = 48; d0 < 64; d0 += 4) {
      int d = d0 + dr;
      sQ[t * 72 + d] = 0;
      sK[t * 72 + d] = 0;
    }
    for (int idx = tid; idx < 384; idx += 256) {
      int d = idx >> 3, c8 = idx & 7;
      *(uint4*)&sV[d * 72 + c8 * 8] =
          *(const uint4*)&qkv[(size_t)(768 + h * 48 + d) * NPIX + wb + c8 * 8];
    }
  }
  __syncthreads();

  const int wave = tid >> 6, lane = tid & 63;
  const int l16 = lane & 15, quad = lane >> 4;
  const int tb = wave * 16;

  // S = Q K^T (K-dim = d, padded to 64)
  floatx4 sacc[4];
#pragma unroll
  for (int nt = 0; nt < 4; ++nt) sacc[nt] = 0.f;
#pragma unroll
  for (int s = 0; s < 2; ++s) {
    bf16x8 aq = *(const bf16x8*)&sQ[(tb + l16) * 72 + s * 32 + quad * 8];
#pragma unroll
    for (int nt = 0; nt < 4; ++nt) {
      bf16x8 bk = *(const bf16x8*)&sK[(nt * 16 + l16) * 72 + s * 32 + quad * 8];
      sacc[nt] = mfma_bf16(aq, bk, sacc[nt]);
    }
  }
  // softmax over u (rows live on 16 lanes sharing quad, x 4 col-tiles)
#pragma unroll
  for (int r = 0; r < 4; ++r) {
    float v0 = sacc[0][r] * SCALE, v1 = sacc[1][r] * SCALE;
    float v2 = sacc[2][r] * SCALE, v3 = sacc[3][r] * SCALE;
    float mx = fmaxf(fmaxf(v0, v1), fmaxf(v2, v3));
    mx = fmaxf(mx, __shfl_xor(mx, 1));
    mx = fmaxf(mx, __shfl_xor(mx, 2));
    mx = fmaxf(mx, __shfl_xor(mx, 4));
    mx = fmaxf(mx, __shfl_xor(mx, 8));
    float p0 = __expf(v0 - mx), p1 = __expf(v1 - mx);
    float p2 = __expf(v2 - mx), p3 = __expf(v3 - mx);
    float sum = p0 + p1 + p2 + p3;
    sum += __shfl_xor(sum, 1);
    sum += __shfl_xor(sum, 2);
    sum += __shfl_xor(sum, 4);
    sum += __shfl_xor(sum, 8);
    float inv = 1.f / sum;
    int t = tb + quad * 4 + r;
    sP[t * 72 + 0 * 16 + l16] = f2b(p0 * inv);
    sP[t * 72 + 1 * 16 + l16] = f2b(p1 * inv);
    sP[t * 72 + 2 * 16 + l16] = f2b(p2 * inv);
    sP[t * 72 + 3 * 16 + l16] = f2b(p3 * inv);
  }
  __syncthreads();

  // O = P V  (K-dim = u = 64, N-dim = d = 48)
  floatx4 oacc[3];
#pragma unroll
  for (int nt = 0; nt < 3; ++nt) oacc[nt] = 0.f;
#pragma unroll
  for (int s = 0; s < 2; ++s) {
    bf16x8 ap = *(const bf16x8*)&sP[(tb + l16) * 72 + s * 32 + quad * 8];
#pragma unroll
    for (int nt = 0; nt < 3; ++nt) {
      bf16x8 bv = *(const bf16x8*)&sV[(nt * 16 + l16) * 72 + s * 32 + quad * 8];
      oacc[nt] = mfma_bf16(ap, bv, oacc[nt]);
    }
  }
#pragma unroll
  for (int nt = 0; nt < 3; ++nt) {
#pragma unroll
    for (int r = 0; r < 4; ++r) {
      int t = tb + quad * 4 + r;
      int d = nt * 16 + l16;
      ao[((size_t)(wb + t)) * 384 + h * 48 + d] = f2b(oacc[nt][r]);
    }
  }
}

// ---------------------------------------------------------------- launch
extern "C" void kernel_launch(void* const* d_in, const int* in_sizes, int n_in,
                              void* d_out, int out_size, void* d_ws, size_t ws_size,
                              hipStream_t stream) {
  const float* x  = (const float*)d_in[0];
  const float* wq = (const float*)d_in[1];
  const float* wp = (const float*)d_in[2];
  float* out = (float*)d_out;

  char* ws = (char*)d_ws;
  // workspace layout (bytes): needs ~504.5 MB
  unsigned short* xT  = (unsigned short*)(ws);                          // 100,663,296
  unsigned short* qkv = (unsigned short*)(ws + 100663296ull);           // 301,989,888
  unsigned short* ao  = (unsigned short*)(ws + 402653184ull);           // 100,663,296
  unsigned short* wqb = (unsigned short*)(ws + 503316480ull);           //     884,736
  unsigned short* wpb = (unsigned short*)(ws + 504201216ull);           //     294,912

  wcvt<<<1728, 256, 0, stream>>>(wq, wp, wqb, wpb);
  transpose_cast<<<6144, 256, 0, stream>>>(x, xT);
  gemm_bt<0><<<dim3(1024, 9), 256, 0, stream>>>(wqb, xT, qkv, 1152, NPIX, KDIM);
  attn_kernel<<<16384, 256, 0, stream>>>(qkv, ao);
  gemm_bt<1><<<dim3(1024, 3), 256, 0, stream>>>(wpb, ao, out, 384, NPIX, KDIM);
}